// Round 8
// baseline (222.253 us; speedup 1.0000x reference)
//
#include <hip/hip_runtime.h>

// Ragged gather-to-padded for SparseConvUnet preprocessing.
// feature: [Nrows=N*14, 128] f32 packed; atom_num: [N] int32 in [0,14);
// out = concat( padded [N,14,128] f32 (zero where slot>=atom_num), label as f32 [N] ).
//
// R8: R6 grid (512x1024, fully resident, 512 lockstep streams) + burst-shaped
// inner loop: scalar-uniform gated loads (readfirstlane cnt/off) issued
// back-to-back into named regs, cndmask boundary cleanup, then 7 stores.
// Per residue: ~7KB read burst then 7KB write burst, no exec-mask branches.

#define MAX_ATOMS 14
#define F4_PER_ROW 32                       // 128 floats = 32 float4
#define F4_PER_RES (MAX_ATOMS * F4_PER_ROW) // 448 = 7 * 64
#define TILE 16                             // residues per block-iteration (= waves/block)
#define GBLOCKS 512
#define GTHREADS 1024

typedef float f32x4 __attribute__((ext_vector_type(4)));

// ---- kernel A: per-256-residue chunk sums ----
__global__ __launch_bounds__(256) void k_sums(const int* __restrict__ atom_num,
                                              int n, int* __restrict__ sums) {
    __shared__ int lds[256];
    int t = threadIdx.x;
    int r = blockIdx.x * 256 + t;
    lds[t] = (r < n) ? atom_num[r] : 0;
    __syncthreads();
    for (int d = 128; d > 0; d >>= 1) {
        if (t < d) lds[t] += lds[t + d];
        __syncthreads();
    }
    if (t == 0) sums[blockIdx.x] = lds[0];
}

// ---- kernel B: per-residue offsets + label cast ----
__global__ __launch_bounds__(256) void k_prep(const int* __restrict__ atom_num,
                                              const int* __restrict__ sums,
                                              const int* __restrict__ label,
                                              int n,
                                              int* __restrict__ offsets,
                                              float* __restrict__ out_label) {
    __shared__ int red[256];
    __shared__ int scn[256];
    int t = threadIdx.x;
    int b = blockIdx.x;
    int part = 0;
    for (int j = t; j < b; j += 256) part += sums[j];
    red[t] = part;
    __syncthreads();
    for (int d = 128; d > 0; d >>= 1) {
        if (t < d) red[t] += red[t + d];
        __syncthreads();
    }
    int base = red[0];
    int r = b * 256 + t;
    int v = (r < n) ? atom_num[r] : 0;
    scn[t] = v;
    __syncthreads();
    for (int d = 1; d < 256; d <<= 1) {
        int add = (t >= d) ? scn[t - d] : 0;
        __syncthreads();
        scn[t] += add;
        __syncthreads();
    }
    if (r < n) {
        offsets[r] = base + scn[t] - v;
        out_label[r] = (float)label[r];     // harness reads d_out as f32
    }
}

// ---- kernel C: streaming gather, burst-shaped ----
__global__ __launch_bounds__(GTHREADS, 8) void k_gather(
        const f32x4* __restrict__ feat,
        const int* __restrict__ atom_num,
        const int* __restrict__ offsets,
        f32x4* __restrict__ out,
        int n, int ntiles) {
    int w       = threadIdx.x >> 6;        // wave 0..15
    int lane    = threadIdx.x & 63;
    int halfrow = lane >> 5;               // which row of the lane's pair

    const f32x4 z = (f32x4)0.f;

    for (int tile = blockIdx.x; tile < ntiles; tile += GBLOCKS) {
        int r = tile * TILE + w;           // one residue per wave
        if (r < n) {
            // wave-uniform scalars -> SGPR, so load gates are scalar branches
            int off = __builtin_amdgcn_readfirstlane(offsets[r]);
            int cnt = __builtin_amdgcn_readfirstlane(atom_num[r]);
            int pairs = (cnt + 1) >> 1;    // row-pairs containing any valid row

            const f32x4* fp = feat + (size_t)off * F4_PER_ROW + lane;
            f32x4* op = out + (size_t)r * F4_PER_RES + lane;

            // back-to-back load burst (boundary row read is in-bounds:
            // off+cnt < N*14 rows allocated)
            f32x4 v0 = z, v1 = z, v2 = z, v3 = z, v4 = z, v5 = z, v6 = z;
            if (pairs > 0) v0 = __builtin_nontemporal_load(fp + 0 * 64);
            if (pairs > 1) v1 = __builtin_nontemporal_load(fp + 1 * 64);
            if (pairs > 2) v2 = __builtin_nontemporal_load(fp + 2 * 64);
            if (pairs > 3) v3 = __builtin_nontemporal_load(fp + 3 * 64);
            if (pairs > 4) v4 = __builtin_nontemporal_load(fp + 4 * 64);
            if (pairs > 5) v5 = __builtin_nontemporal_load(fp + 5 * 64);
            if (pairs > 6) v6 = __builtin_nontemporal_load(fp + 6 * 64);

            // boundary cleanup: zero lanes whose row >= cnt (cndmask, no branch)
            v0 = (0  + halfrow < cnt) ? v0 : z;
            v1 = (2  + halfrow < cnt) ? v1 : z;
            v2 = (4  + halfrow < cnt) ? v2 : z;
            v3 = (6  + halfrow < cnt) ? v3 : z;
            v4 = (8  + halfrow < cnt) ? v4 : z;
            v5 = (10 + halfrow < cnt) ? v5 : z;
            v6 = (12 + halfrow < cnt) ? v6 : z;

            // back-to-back store burst
            __builtin_nontemporal_store(v0, op + 0 * 64);
            __builtin_nontemporal_store(v1, op + 1 * 64);
            __builtin_nontemporal_store(v2, op + 2 * 64);
            __builtin_nontemporal_store(v3, op + 3 * 64);
            __builtin_nontemporal_store(v4, op + 4 * 64);
            __builtin_nontemporal_store(v5, op + 5 * 64);
            __builtin_nontemporal_store(v6, op + 6 * 64);
        }
    }
}

extern "C" void kernel_launch(void* const* d_in, const int* in_sizes, int n_in,
                              void* d_out, int out_size, void* d_ws, size_t ws_size,
                              hipStream_t stream) {
    const float* feature = (const float*)d_in[0];
    const int* atom_num  = (const int*)d_in[1];
    const int* label     = (const int*)d_in[2];
    const int n = in_sizes[1];               // N_res = 100000

    float* out = (float*)d_out;
    float* out_label = out + (size_t)n * MAX_ATOMS * 128;

    int nb = (n + 255) / 256;                // 391
    int* ws_sums    = (int*)d_ws;            // nb ints
    int* ws_offsets = ws_sums + nb;          // n ints

    k_sums<<<nb, 256, 0, stream>>>(atom_num, n, ws_sums);
    k_prep<<<nb, 256, 0, stream>>>(atom_num, ws_sums, label, n,
                                   ws_offsets, out_label);

    int ntiles = (n + TILE - 1) / TILE;      // 6250
    k_gather<<<GBLOCKS, GTHREADS, 0, stream>>>(
        (const f32x4*)feature, atom_num, ws_offsets,
        (f32x4*)out, n, ntiles);
}

// Round 9
// 221.667 us; speedup vs baseline: 1.0026x; 1.0026x over previous
//
#include <hip/hip_runtime.h>

// Ragged gather-to-padded for SparseConvUnet preprocessing.
// feature: [Nrows, 128] f32 packed; atom_num: [N] int32 in [0,14);
// out = concat( padded [N,14,128] f32 (zero where slot>=atom_num), label as f32 [N] ).
//
// R9: single-variable A/B vs R6 — BLOCKED tile partition. Same 512x1024
// resident grid, same nt+nt per-lane-masked inner loop; but each block owns
// a CONTIGUOUS run of tiles (~1.4MB of output) instead of a stride-512
// interleave. 512 write streams spread across the full output (bank-
// decorrelated) vs R6's compact 58MB front.

#define MAX_ATOMS 14
#define F4_PER_ROW 32                       // 128 floats = 32 float4
#define F4_PER_RES (MAX_ATOMS * F4_PER_ROW) // 448 = 7 * 64
#define TILE 16                             // residues per block-iteration (= waves/block)
#define GBLOCKS 512
#define GTHREADS 1024

typedef float f32x4 __attribute__((ext_vector_type(4)));

// ---- kernel A: per-256-residue chunk sums ----
__global__ __launch_bounds__(256) void k_sums(const int* __restrict__ atom_num,
                                              int n, int* __restrict__ sums) {
    __shared__ int lds[256];
    int t = threadIdx.x;
    int r = blockIdx.x * 256 + t;
    lds[t] = (r < n) ? atom_num[r] : 0;
    __syncthreads();
    for (int d = 128; d > 0; d >>= 1) {
        if (t < d) lds[t] += lds[t + d];
        __syncthreads();
    }
    if (t == 0) sums[blockIdx.x] = lds[0];
}

// ---- kernel B: per-residue offsets + label cast ----
__global__ __launch_bounds__(256) void k_prep(const int* __restrict__ atom_num,
                                              const int* __restrict__ sums,
                                              const int* __restrict__ label,
                                              int n,
                                              int* __restrict__ offsets,
                                              float* __restrict__ out_label) {
    __shared__ int red[256];
    __shared__ int scn[256];
    int t = threadIdx.x;
    int b = blockIdx.x;
    int part = 0;
    for (int j = t; j < b; j += 256) part += sums[j];
    red[t] = part;
    __syncthreads();
    for (int d = 128; d > 0; d >>= 1) {
        if (t < d) red[t] += red[t + d];
        __syncthreads();
    }
    int base = red[0];
    int r = b * 256 + t;
    int v = (r < n) ? atom_num[r] : 0;
    scn[t] = v;
    __syncthreads();
    for (int d = 1; d < 256; d <<= 1) {
        int add = (t >= d) ? scn[t - d] : 0;
        __syncthreads();
        scn[t] += add;
        __syncthreads();
    }
    if (r < n) {
        offsets[r] = base + scn[t] - v;
        out_label[r] = (float)label[r];     // harness reads d_out as f32
    }
}

// ---- kernel C: streaming gather, blocked contiguous partition ----
__global__ __launch_bounds__(GTHREADS, 8) void k_gather(
        const f32x4* __restrict__ feat,
        const int* __restrict__ atom_num,
        const int* __restrict__ offsets,
        f32x4* __restrict__ out,
        int n, int ntiles, int tpb) {
    int w       = threadIdx.x >> 6;        // wave 0..15
    int lane    = threadIdx.x & 63;
    int halfrow = lane >> 5;               // which row of the lane's pair

    int t0 = blockIdx.x * tpb;
    int t1 = t0 + tpb;
    if (t1 > ntiles) t1 = ntiles;

    for (int tile = t0; tile < t1; ++tile) {
        int r = tile * TILE + w;           // one residue per wave
        if (r < n) {
            int off = offsets[r];          // wave-uniform broadcast load (L2-hot)
            int cnt = atom_num[r];
            const f32x4* fp = feat + (size_t)off * F4_PER_ROW + lane;
            f32x4* op = out + (size_t)r * F4_PER_RES + lane;
            #pragma unroll
            for (int i = 0; i < 7; ++i) {
                f32x4 v = (f32x4)0.f;
                if (2 * i + halfrow < cnt)
                    v = __builtin_nontemporal_load(fp + i * 64);
                __builtin_nontemporal_store(v, op + i * 64);
            }
        }
    }
}

extern "C" void kernel_launch(void* const* d_in, const int* in_sizes, int n_in,
                              void* d_out, int out_size, void* d_ws, size_t ws_size,
                              hipStream_t stream) {
    const float* feature = (const float*)d_in[0];
    const int* atom_num  = (const int*)d_in[1];
    const int* label     = (const int*)d_in[2];
    const int n = in_sizes[1];               // N_res = 100000

    float* out = (float*)d_out;
    float* out_label = out + (size_t)n * MAX_ATOMS * 128;

    int nb = (n + 255) / 256;                // 391
    int* ws_sums    = (int*)d_ws;            // nb ints
    int* ws_offsets = ws_sums + nb;          // n ints

    k_sums<<<nb, 256, 0, stream>>>(atom_num, n, ws_sums);
    k_prep<<<nb, 256, 0, stream>>>(atom_num, ws_sums, label, n,
                                   ws_offsets, out_label);

    int ntiles = (n + TILE - 1) / TILE;      // 6250
    int tpb = (ntiles + GBLOCKS - 1) / GBLOCKS; // 13
    k_gather<<<GBLOCKS, GTHREADS, 0, stream>>>(
        (const f32x4*)feature, atom_num, ws_offsets,
        (f32x4*)out, n, ntiles, tpb);
}

// Round 10
// 215.276 us; speedup vs baseline: 1.0324x; 1.0297x over previous
//
#include <hip/hip_runtime.h>

// Ragged gather-to-padded for SparseConvUnet preprocessing.
// feature: [Nrows, 128] f32 packed; atom_num: [N] int32 in [0,14);
// out = concat( padded [N,14,128] f32 (zero where slot>=atom_num), label as f32 [N] ).
//
// R10: single-variable A/B vs R6 — stores PLAIN (L2 write-back) instead of nt.
// Same 512x1024 resident grid, stride-interleaved tiles (compact front),
// nt loads (L2 stays write-dedicated). Tests whether the fill-kernel regime
// (plain stores + compact front) beats the nt write-combine path.

#define MAX_ATOMS 14
#define F4_PER_ROW 32                       // 128 floats = 32 float4
#define F4_PER_RES (MAX_ATOMS * F4_PER_ROW) // 448 = 7 * 64
#define TILE 16                             // residues per block-iteration (= waves/block)
#define GBLOCKS 512
#define GTHREADS 1024

typedef float f32x4 __attribute__((ext_vector_type(4)));

// ---- kernel A: per-256-residue chunk sums ----
__global__ __launch_bounds__(256) void k_sums(const int* __restrict__ atom_num,
                                              int n, int* __restrict__ sums) {
    __shared__ int lds[256];
    int t = threadIdx.x;
    int r = blockIdx.x * 256 + t;
    lds[t] = (r < n) ? atom_num[r] : 0;
    __syncthreads();
    for (int d = 128; d > 0; d >>= 1) {
        if (t < d) lds[t] += lds[t + d];
        __syncthreads();
    }
    if (t == 0) sums[blockIdx.x] = lds[0];
}

// ---- kernel B: per-residue offsets + label cast ----
__global__ __launch_bounds__(256) void k_prep(const int* __restrict__ atom_num,
                                              const int* __restrict__ sums,
                                              const int* __restrict__ label,
                                              int n,
                                              int* __restrict__ offsets,
                                              float* __restrict__ out_label) {
    __shared__ int red[256];
    __shared__ int scn[256];
    int t = threadIdx.x;
    int b = blockIdx.x;
    int part = 0;
    for (int j = t; j < b; j += 256) part += sums[j];
    red[t] = part;
    __syncthreads();
    for (int d = 128; d > 0; d >>= 1) {
        if (t < d) red[t] += red[t + d];
        __syncthreads();
    }
    int base = red[0];
    int r = b * 256 + t;
    int v = (r < n) ? atom_num[r] : 0;
    scn[t] = v;
    __syncthreads();
    for (int d = 1; d < 256; d <<= 1) {
        int add = (t >= d) ? scn[t - d] : 0;
        __syncthreads();
        scn[t] += add;
        __syncthreads();
    }
    if (r < n) {
        offsets[r] = base + scn[t] - v;
        out_label[r] = (float)label[r];     // harness reads d_out as f32
    }
}

// ---- kernel C: streaming gather, resident grid, plain stores ----
__global__ __launch_bounds__(GTHREADS, 8) void k_gather(
        const f32x4* __restrict__ feat,
        const int* __restrict__ atom_num,
        const int* __restrict__ offsets,
        f32x4* __restrict__ out,
        int n, int ntiles) {
    int w       = threadIdx.x >> 6;        // wave 0..15
    int lane    = threadIdx.x & 63;
    int halfrow = lane >> 5;               // which row of the lane's pair

    for (int tile = blockIdx.x; tile < ntiles; tile += GBLOCKS) {
        int r = tile * TILE + w;           // one residue per wave
        if (r < n) {
            int off = offsets[r];          // wave-uniform broadcast load (L2-hot)
            int cnt = atom_num[r];
            const f32x4* fp = feat + (size_t)off * F4_PER_ROW + lane;
            f32x4* op = out + (size_t)r * F4_PER_RES + lane;
            #pragma unroll
            for (int i = 0; i < 7; ++i) {
                f32x4 v = (f32x4)0.f;
                if (2 * i + halfrow < cnt)
                    v = __builtin_nontemporal_load(fp + i * 64);
                op[i * 64] = v;            // plain store (L2 write-back)
            }
        }
    }
}

extern "C" void kernel_launch(void* const* d_in, const int* in_sizes, int n_in,
                              void* d_out, int out_size, void* d_ws, size_t ws_size,
                              hipStream_t stream) {
    const float* feature = (const float*)d_in[0];
    const int* atom_num  = (const int*)d_in[1];
    const int* label     = (const int*)d_in[2];
    const int n = in_sizes[1];               // N_res = 100000

    float* out = (float*)d_out;
    float* out_label = out + (size_t)n * MAX_ATOMS * 128;

    int nb = (n + 255) / 256;                // 391
    int* ws_sums    = (int*)d_ws;            // nb ints
    int* ws_offsets = ws_sums + nb;          // n ints

    k_sums<<<nb, 256, 0, stream>>>(atom_num, n, ws_sums);
    k_prep<<<nb, 256, 0, stream>>>(atom_num, ws_sums, label, n,
                                   ws_offsets, out_label);

    int ntiles = (n + TILE - 1) / TILE;      // 6250
    k_gather<<<GBLOCKS, GTHREADS, 0, stream>>>(
        (const f32x4*)feature, atom_num, ws_offsets,
        (f32x4*)out, n, ntiles);
}